// Round 2
// baseline (1883.272 us; speedup 1.0000x reference)
//
#include <hip/hip_runtime.h>
#include <stdint.h>

// ----------------------------------------------------------------------------
// HebbianLayer on MI355X (gfx950).
// B=8, T=4096, D=768, d_inner=1536, CHUNK=64, Nc=64.
// bf16 MFMA everywhere matmul-shaped; fp32 elementwise. Workspace kept under
// ~266 MB via liveness overlays (previous 667 MB layout suspected of ws
// overflow -> GPU fault -> SIGABRT).
// ----------------------------------------------------------------------------

typedef short bf16s;                                            // raw bf16 bits
typedef __attribute__((ext_vector_type(8))) short short8;       // 4 VGPR mfma frag
typedef __attribute__((ext_vector_type(4))) float f32x4;        // mfma acc

#define DEVINL __device__ __forceinline__

DEVINL float bf2f(short s) {
    union { unsigned u; float f; } v; v.u = ((unsigned)(unsigned short)s) << 16; return v.f;
}
DEVINL short f2bf(float f) {
    union { float f; unsigned u; } v; v.f = f;
    unsigned r = v.u + 0x7fffu + ((v.u >> 16) & 1u);            // RNE
    return (short)(r >> 16);
}

// async global->LDS, 16B per lane. LDS dest must be wave-uniform.
DEVINL void glds16(void* lds, const void* g) {
    __builtin_amdgcn_global_load_lds(
        (const __attribute__((address_space(1))) void*)g,
        (__attribute__((address_space(3))) void*)lds, 16, 0, 0);
}

// Stage a 64-row x 64-col bf16 tile into LDS with XOR slot swizzle:
// row r holds 8 slots of 8 elems; slot s contains fragment f = s ^ (r&7).
DEVINL void stage64(bf16s* lds, const bf16s* g, long gstride, int tid) {
    int w = tid >> 6;
    int r0 = tid >> 3;                 // 0..31
    int s  = tid & 7;
#pragma unroll
    for (int p = 0; p < 2; ++p) {
        int r = p * 32 + r0;
        int f = s ^ (r & 7);
        glds16(lds + p * 2048 + w * 512, g + (long)r * gstride + f * 8);
    }
}

// Read an A/B fragment from a swizzled 64-col tile.
// mfma_f32_16x16x32 operand: lane holds [row][k = (lane>>4)*8 + j].
DEVINL short8 fragr(const bf16s* t, int row, int kk, int q) {
    int f = kk * 4 + q;
    return *(const short8*)(t + row * 64 + ((f ^ (row & 7)) * 8));
}

#define MFMA(a, b, c) __builtin_amdgcn_mfma_f32_16x16x32_bf16((a), (b), (c), 0, 0, 0)

// ---------------------------------------------------------------------------
// K0: weight casts (fp32 -> bf16). w_pg = [proj_w ; gate_w] rows (3072x768).
// ---------------------------------------------------------------------------
__global__ __launch_bounds__(256) void cast_w_kernel(
    const float* __restrict__ proj, const float* __restrict__ gate,
    const float* __restrict__ op, const float* __restrict__ wr, const float* __restrict__ rd,
    bf16s* __restrict__ w_pg, bf16s* __restrict__ w_op, bf16s* __restrict__ w_wr,
    bf16s* __restrict__ w_rd) {
    long i = (long)blockIdx.x * 256 + threadIdx.x;
    if (i < 1179648)        w_pg[i] = f2bf(proj[i]);
    else if (i < 2359296)   w_pg[i] = f2bf(gate[i - 1179648]);
    else if (i < 3538944)   w_op[i - 2359296] = f2bf(op[i - 2359296]);
    else if (i < 4128768)   w_wr[i - 3538944] = f2bf(wr[i - 3538944]);
    else if (i < 4718592)   w_rd[i - 4128768] = f2bf(rd[i - 4128768]);
}

// ---------------------------------------------------------------------------
// K1: RMSNorm + cast. One block per row (768 elems).
// ---------------------------------------------------------------------------
__global__ __launch_bounds__(256) void rmsnorm_kernel(
    const float* __restrict__ x, const float* __restrict__ w, bf16s* __restrict__ xn) {
    long row = blockIdx.x;
    const float* xr = x + row * 768;
    int tid = threadIdx.x;
    float v0 = xr[tid], v1 = xr[tid + 256], v2 = xr[tid + 512];
    float ss = v0 * v0 + v1 * v1 + v2 * v2;
#pragma unroll
    for (int off = 32; off; off >>= 1) ss += __shfl_down(ss, off);
    __shared__ float p[4];
    if ((tid & 63) == 0) p[tid >> 6] = ss;
    __syncthreads();
    float tot = p[0] + p[1] + p[2] + p[3];
    float s = rsqrtf(tot * (1.0f / 768.0f) + 1e-5f);
    bf16s* o = xn + row * 768;
    o[tid]       = f2bf(v0 * s * w[tid]);
    o[tid + 256] = f2bf(v1 * s * w[tid + 256]);
    o[tid + 512] = f2bf(v2 * s * w[tid + 512]);
}

// ---------------------------------------------------------------------------
// GEMM: C[M,N] = A[M,K] @ B[N,K]^T. 128x128 tile, BK=64, 4 waves 2x2,
// each wave 64x64 (4x4 16-tiles).
// MODE 0: store bf16.   MODE 1: d_out = x + bf2f(outres) + exp(la)*acc (f32).
// ---------------------------------------------------------------------------
template <int MODE>
__global__ __launch_bounds__(256, 2) void gemm_kernel(
    const bf16s* __restrict__ A, const bf16s* __restrict__ B, int K, int N,
    bf16s* __restrict__ Cb, const float* __restrict__ xres,
    const bf16s* __restrict__ outres, const float* __restrict__ p_la,
    float* __restrict__ Cout) {
    __shared__ bf16s sA[128 * 64];
    __shared__ bf16s sB[128 * 64];
    const int tid = threadIdx.x;
    const int wave = tid >> 6, lane = tid & 63;
    const int wm = wave >> 1, wn = wave & 1;
    const int ln15 = lane & 15, q = lane >> 4;
    const long m0 = (long)blockIdx.y * 128, n0 = (long)blockIdx.x * 128;
    const int sr = tid >> 3;
    const int sf = (tid & 7) ^ (sr & 7);
    const bf16s* gA = A + (m0 + sr) * K + sf * 8;
    const bf16s* gB = B + (n0 + sr) * K + sf * 8;
    f32x4 acc[4][4] = {};
    const int nkt = K >> 6;
    for (int kt = 0; kt < nkt; ++kt) {
        __syncthreads();
#pragma unroll
        for (int p = 0; p < 4; ++p) {
            glds16(sA + p * 2048 + wave * 512, gA + (long)p * 32 * K);
            glds16(sB + p * 2048 + wave * 512, gB + (long)p * 32 * K);
        }
        gA += 64; gB += 64;
        asm volatile("s_waitcnt vmcnt(0)" ::: "memory");
        __syncthreads();
#pragma unroll
        for (int kk = 0; kk < 2; ++kk) {
            short8 af[4], bf_[4];
#pragma unroll
            for (int i = 0; i < 4; ++i) af[i] = fragr(sA, wm * 64 + i * 16 + ln15, kk, q);
#pragma unroll
            for (int j = 0; j < 4; ++j) bf_[j] = fragr(sB, wn * 64 + j * 16 + ln15, kk, q);
#pragma unroll
            for (int i = 0; i < 4; ++i)
#pragma unroll
                for (int j = 0; j < 4; ++j) acc[i][j] = MFMA(af[i], bf_[j], acc[i][j]);
        }
    }
    float alpha = 0.f;
    if (MODE == 1) alpha = __expf(p_la[0]);
#pragma unroll
    for (int i = 0; i < 4; ++i)
#pragma unroll
        for (int j = 0; j < 4; ++j) {
            long mb = m0 + wm * 64 + i * 16 + q * 4;
            long nc = n0 + wn * 64 + j * 16 + ln15;
#pragma unroll
            for (int e = 0; e < 4; ++e) {
                long m = mb + e;
                float v = acc[i][j][e];
                if (MODE == 0) {
                    Cb[m * N + nc] = f2bf(v);
                } else {
                    long idx = m * 768 + nc;
                    Cout[idx] = xres[idx] + bf2f(outres[idx]) + alpha * v;
                }
            }
        }
}

// ---------------------------------------------------------------------------
// K3: depthwise causal conv(4) + bias + SiLU, gated by SiLU(gate).
// One block per (local) sequence position, 192 threads x 8 channels.
// Halved over M at a batch boundary, so tl = l & 4095 stays valid.
// ---------------------------------------------------------------------------
__global__ __launch_bounds__(192) void conv_kernel(
    const bf16s* __restrict__ pg, const float* __restrict__ cw,
    const float* __restrict__ cb, bf16s* __restrict__ vg) {
    long l = blockIdx.x;
    int e0 = threadIdx.x * 8;
    int tl = (int)(l & 4095);
    const bf16s* base = pg + l * 3072;
    float v[8];
#pragma unroll
    for (int i = 0; i < 8; ++i) v[i] = cb[e0 + i];
#pragma unroll
    for (int j = 0; j < 4; ++j) {
        int dt = j - 3;
        if (tl + dt >= 0) {
            short8 s8 = *(const short8*)(base + (long)dt * 3072 + e0);
#pragma unroll
            for (int i = 0; i < 8; ++i) v[i] += bf2f(s8[i]) * cw[(e0 + i) * 4 + j];
        }
    }
    short8 g8 = *(const short8*)(base + 1536 + e0);
    short8 o;
#pragma unroll
    for (int i = 0; i < 8; ++i) {
        float vv = v[i];
        float sv = vv / (1.0f + __expf(-vv));
        float gg = bf2f(g8[i]);
        float sg = gg / (1.0f + __expf(-gg));
        o[i] = f2bf(sv * sg);
    }
    *(short8*)(vg + l * 1536 + e0) = o;
}

// ---------------------------------------------------------------------------
// K5: transpose [b][t][e] -> [b][e][t], optional shift (t -> t-1, zero fill)
// and optional gw scale gamma^(63 - t%64). bf16 -> bf16.
// ---------------------------------------------------------------------------
template <int SHIFT, int GW>
__global__ __launch_bounds__(256) void transpose_kernel(
    const bf16s* __restrict__ src, bf16s* __restrict__ dst,
    const float* __restrict__ p_decay) {
    int b = blockIdx.z;
    long t0 = (long)blockIdx.y * 64, e0 = (long)blockIdx.x * 64;
    __shared__ bf16s tile[64][72];
    int tid = threadIdx.x;
    int r = tid >> 2, cs = (tid & 3) * 16;
    long tsrc = t0 + r - SHIFT;
    if (tsrc >= 0) {
        const bf16s* s = src + ((long)b * 4096 + tsrc) * 768 + e0 + cs;
        short8 v0 = *(const short8*)s;
        short8 v1 = *(const short8*)(s + 8);
        if (GW) {
            float gm = 1.0f / (1.0f + __expf(-p_decay[0]));
            float gwf = exp2f(__log2f(gm) * (float)(63 - (int)(tsrc & 63)));
#pragma unroll
            for (int i = 0; i < 8; ++i) {
                tile[r][cs + i]     = f2bf(bf2f(v0[i]) * gwf);
                tile[r][cs + 8 + i] = f2bf(bf2f(v1[i]) * gwf);
            }
        } else {
#pragma unroll
            for (int i = 0; i < 8; ++i) {
                tile[r][cs + i]     = v0[i];
                tile[r][cs + 8 + i] = v1[i];
            }
        }
    } else {
#pragma unroll
        for (int i = 0; i < 16; ++i) tile[r][cs + i] = 0;
    }
    __syncthreads();
    int er = tid >> 2, ts = (tid & 3) * 16;
    short8 a, bb;
#pragma unroll
    for (int i = 0; i < 8; ++i) a[i] = tile[ts + i][er];
#pragma unroll
    for (int i = 0; i < 8; ++i) bb[i] = tile[ts + 8 + i][er];
    bf16s* d = dst + ((long)b * 768 + e0 + er) * 4096 + t0 + ts;
    *(short8*)d = a;
    *(short8*)(d + 8) = bb;
}

// ---------------------------------------------------------------------------
// K7: P'[b,j][c][c'] = bf16( (r_c . k_c') * gamma^(c-64) * (c>c') ).
// gw on values folded out: intra = P' @ (v*gw) == reference intra exactly.
// ---------------------------------------------------------------------------
__global__ __launch_bounds__(256) void pmat_kernel(
    const bf16s* __restrict__ ob, const float* __restrict__ p_decay,
    bf16s* __restrict__ P) {
    int b = blockIdx.y, j = blockIdx.x;
    long t0 = (long)j * 64;
    __shared__ bf16s sA[64 * 64];
    __shared__ bf16s sB[64 * 64];
    int tid = threadIdx.x;
    int wave = tid >> 6, lane = tid & 63, ln15 = lane & 15, q = lane >> 4;
    int wm = wave >> 1, wn = wave & 1;
    f32x4 acc[2][2] = {};
    const bf16s* gr = ob + ((long)b * 4096 + t0) * 768;
    const bf16s* gk = gr - 768;                     // shifted keys (t-1)
    for (int kt = 0; kt < 12; ++kt) {
        __syncthreads();
        stage64(sA, gr + kt * 64, 768, tid);
        stage64(sB, gk + kt * 64, 768, tid);
        asm volatile("s_waitcnt vmcnt(0)" ::: "memory");
        __syncthreads();
        if (j == 0) {                       // k row c'=0 is t=-1 -> zero
            if (tid < 8) { short8 zz = {0,0,0,0,0,0,0,0}; ((short8*)sB)[tid] = zz; }
            __syncthreads();
        }
#pragma unroll
        for (int kk = 0; kk < 2; ++kk) {
            short8 a0 = fragr(sA, wm * 32 + ln15, kk, q);
            short8 a1 = fragr(sA, wm * 32 + 16 + ln15, kk, q);
            short8 b0 = fragr(sB, wn * 32 + ln15, kk, q);
            short8 b1 = fragr(sB, wn * 32 + 16 + ln15, kk, q);
            acc[0][0] = MFMA(a0, b0, acc[0][0]);
            acc[0][1] = MFMA(a0, b1, acc[0][1]);
            acc[1][0] = MFMA(a1, b0, acc[1][0]);
            acc[1][1] = MFMA(a1, b1, acc[1][1]);
        }
    }
    float gm = 1.0f / (1.0f + __expf(-p_decay[0]));
    float lg = __log2f(gm);
    bf16s* Pb = P + ((long)b * 64 + j) * 4096;
#pragma unroll
    for (int i = 0; i < 2; ++i)
#pragma unroll
        for (int jj = 0; jj < 2; ++jj)
#pragma unroll
            for (int e = 0; e < 4; ++e) {
                int c  = wm * 32 + i * 16 + q * 4 + e;
                int cp = wn * 32 + jj * 16 + ln15;
                float val = (c > cp) ? acc[i][jj][e] * exp2f(lg * (float)(c - 64)) : 0.0f;
                Pb[c * 64 + cp] = f2bf(val);
            }
}

// ---------------------------------------------------------------------------
// K8: persistent scan. Block = (b, 32-row slice of W). W resident in LDS.
// Per chunk j:
//   A: reads[c,d] = gamma^c * (r_c . W[d,:]) + P' @ vTs     (mfma)
//   B: W[d,e] = gamma^64*W + sum_c vTs[d,c]*kT[e,c]         (mfma)
// W rows are block-private -> no inter-block sync needed.
// ---------------------------------------------------------------------------
__global__ __launch_bounds__(256, 2) void scan_kernel(
    const bf16s* __restrict__ ob, const bf16s* __restrict__ oTs,
    const bf16s* __restrict__ vTs, const bf16s* __restrict__ P,
    bf16s* __restrict__ reads, const float* __restrict__ p_decay) {
    const int b = blockIdx.y, dt = blockIdx.x;
    const int d0 = dt * 32;
    __shared__ bf16s W[32 * 776];
    __shared__ bf16s skb[64 * 64];
    const int tid = threadIdx.x;
    const int wave = tid >> 6, lane = tid & 63, ln15 = lane & 15, q = lane >> 4;
    const int wm = wave >> 1, wn = wave & 1;     // phase A: c-half / d-half
    const int bm = wave & 1;                     // phase B: d-half
    const int bn0 = wave >> 1;                   // phase B: nt in {bn0, bn0+2}
    for (int i = tid; i < 32 * 776; i += 256) W[i] = 0;
    const float gm = 1.0f / (1.0f + __expf(-p_decay[0]));
    const float lg = __log2f(gm);
    const float gC = exp2f(lg * 64.0f);
    float fac[2][4];
#pragma unroll
    for (int mt = 0; mt < 2; ++mt)
#pragma unroll
        for (int e = 0; e < 4; ++e)
            fac[mt][e] = exp2f(lg * (float)(wm * 32 + mt * 16 + q * 4 + e));
    const bf16s* vT_base = vTs + ((long)b * 768 + d0) * 4096;
    const bf16s* oT_base = oTs + (long)b * 768 * 4096;
    const bf16s* ob_base = ob + (long)b * 4096 * 768;
    const bf16s* P_base  = P + (long)b * 64 * 4096;
    for (int j = 0; j < 64; ++j) {
        const long t0 = (long)j * 64;
        __syncthreads();
        // ---- phase A ----
        f32x4 acc0 = {}, acc1 = {};
        for (int kt = 0; kt < 12; ++kt) {
            if (kt) __syncthreads();
            stage64(skb, ob_base + t0 * 768 + kt * 64, 768, tid);
            asm volatile("s_waitcnt vmcnt(0)" ::: "memory");
            __syncthreads();
#pragma unroll
            for (int kk = 0; kk < 2; ++kk) {
                short8 a0 = fragr(skb, wm * 32 + ln15, kk, q);
                short8 a1 = fragr(skb, wm * 32 + 16 + ln15, kk, q);
                short8 bw = *(const short8*)(W + (wn * 16 + ln15) * 776 + kt * 64 + kk * 32 + q * 8);
                acc0 = MFMA(a0, bw, acc0);
                acc1 = MFMA(a1, bw, acc1);
            }
        }
#pragma unroll
        for (int e = 0; e < 4; ++e) { acc0[e] *= fac[0][e]; acc1[e] *= fac[1][e]; }
        {   // intra: A = P' (plain layout), B = vTs — both straight from global
            const bf16s* Pj = P_base + (long)j * 4096;
#pragma unroll
            for (int kk = 0; kk < 2; ++kk) {
                int f8 = kk * 32 + q * 8;
                short8 a0 = *(const short8*)(Pj + (wm * 32 + ln15) * 64 + f8);
                short8 a1 = *(const short8*)(Pj + (wm * 32 + 16 + ln15) * 64 + f8);
                short8 bv = *(const short8*)(vT_base + (long)(wn * 16 + ln15) * 4096 + t0 + f8);
                acc0 = MFMA(a0, bv, acc0);
                acc1 = MFMA(a1, bv, acc1);
            }
        }
#pragma unroll
        for (int mt = 0; mt < 2; ++mt) {
            f32x4 ac = mt ? acc1 : acc0;
#pragma unroll
            for (int e = 0; e < 4; ++e) {
                long t = t0 + wm * 32 + mt * 16 + q * 4 + e;
                reads[((long)b * 4096 + t) * 768 + d0 + wn * 16 + ln15] = f2bf(ac[e]);
            }
        }
        __syncthreads();   // all W reads (inter) done before update writes
        // ---- phase B ----
        short8 av0 = *(const short8*)(vT_base + (long)(bm * 16 + ln15) * 4096 + t0 + q * 8);
        short8 av1 = *(const short8*)(vT_base + (long)(bm * 16 + ln15) * 4096 + t0 + 32 + q * 8);
        for (int et = 0; et < 12; ++et) {
            if (et) __syncthreads();
            stage64(skb, oT_base + (long)et * 64 * 4096 + t0, 4096, tid);
            asm volatile("s_waitcnt vmcnt(0)" ::: "memory");
            __syncthreads();
#pragma unroll
            for (int nt2 = 0; nt2 < 2; ++nt2) {
                int nt = bn0 + nt2 * 2;
                int col = et * 64 + nt * 16 + ln15;
                f32x4 c;
#pragma unroll
                for (int e = 0; e < 4; ++e)
                    c[e] = bf2f(W[(bm * 16 + q * 4 + e) * 776 + col]) * gC;
                short8 b0 = fragr(skb, nt * 16 + ln15, 0, q);
                short8 b1 = fragr(skb, nt * 16 + ln15, 1, q);
                c = MFMA(av0, b0, c);
                c = MFMA(av1, b1, c);
#pragma unroll
                for (int e = 0; e < 4; ++e)
                    W[(bm * 16 + q * 4 + e) * 776 + col] = f2bf(c[e]);
            }
        }
    }
}

// ---------------------------------------------------------------------------
extern "C" void kernel_launch(void* const* d_in, const int* in_sizes, int n_in,
                              void* d_out, int out_size, void* d_ws, size_t ws_size,
                              hipStream_t stream) {
    (void)in_sizes; (void)n_in; (void)out_size;
    const float* x      = (const float*)d_in[0];
    const float* norm_w = (const float*)d_in[1];
    const float* proj_w = (const float*)d_in[2];
    const float* gate_w = (const float*)d_in[3];
    const float* conv_w = (const float*)d_in[4];
    const float* conv_b = (const float*)d_in[5];
    const float* op_w   = (const float*)d_in[6];
    const float* wr_w   = (const float*)d_in[7];
    const float* rd_w   = (const float*)d_in[8];
    const float* decay  = (const float*)d_in[9];
    const float* la     = (const float*)d_in[10];

    // -------- workspace layout (liveness overlays), ~265.3 MB total --------
    char* ws = (char*)d_ws;
    size_t off = 0;
    auto alloc = [&](size_t bytes) { void* p = ws + off; off += (bytes + 255) & ~(size_t)255; return p; };
    bf16s* w_pg = (bf16s*)alloc(3072l * 768 * 2);     // 4.7 MB
    bf16s* w_op = (bf16s*)alloc(768l * 1536 * 2);     // 2.4 MB
    bf16s* w_wr = (bf16s*)alloc(768l * 768 * 2);      // 1.2 MB
    bf16s* w_rd = (bf16s*)alloc(768l * 768 * 2);      // 1.2 MB
    bf16s* P    = (bf16s*)alloc(8l * 64 * 64 * 64 * 2);  // 4.2 MB
    bf16s* R1   = (bf16s*)alloc(32768l * 768 * 2);    // 50.3 MB : xn | oTs
    bf16s* R2   = (bf16s*)alloc(2 * 32768l * 768 * 2);// 100.7 MB: pgH | outb+vb
    bf16s* R3   = (bf16s*)alloc(2 * 32768l * 768 * 2);// 100.7 MB: vg | vTsb+reads
    if (ws_size < off) return;   // diagnostic guard: fail clean, don't fault

    bf16s* xn    = R1;
    bf16s* oTs   = R1;
    bf16s* pgH   = R2;                        // 16384 x 3072 (one M-half)
    bf16s* outb  = R2;
    bf16s* vb    = R2 + 25165824;
    bf16s* vg    = R3;                        // 32768 x 1536
    bf16s* vTsb  = R3;
    bf16s* readsb= R3 + 25165824;

    hipLaunchKernelGGL(cast_w_kernel, dim3(18432), dim3(256), 0, stream,
                       proj_w, gate_w, op_w, wr_w, rd_w, w_pg, w_op, w_wr, w_rd);
    hipLaunchKernelGGL(rmsnorm_kernel, dim3(32768), dim3(256), 0, stream, x, norm_w, xn);
    // proj+gate GEMM + conv, split at the batch-4 boundary (no conv halo)
    for (int h = 0; h < 2; ++h) {
        hipLaunchKernelGGL(HIP_KERNEL_NAME(gemm_kernel<0>), dim3(24, 128), dim3(256), 0, stream,
                           xn + (long)h * 16384 * 768, w_pg, 768, 3072, pgH,
                           (const float*)nullptr, (const bf16s*)nullptr, la, (float*)nullptr);
        hipLaunchKernelGGL(conv_kernel, dim3(16384), dim3(192), 0, stream,
                           pgH, conv_w, conv_b, vg + (long)h * 16384 * 1536);
    }
    hipLaunchKernelGGL(HIP_KERNEL_NAME(gemm_kernel<0>), dim3(6, 256), dim3(256), 0, stream,
                       vg, w_op, 1536, 768, outb,
                       (const float*)nullptr, (const bf16s*)nullptr, la, (float*)nullptr);
    hipLaunchKernelGGL(HIP_KERNEL_NAME(transpose_kernel<1, 0>), dim3(12, 64, 8), dim3(256), 0, stream,
                       outb, oTs, decay);
    hipLaunchKernelGGL(HIP_KERNEL_NAME(gemm_kernel<0>), dim3(6, 256), dim3(256), 0, stream,
                       outb, w_wr, 768, 768, vb,
                       (const float*)nullptr, (const bf16s*)nullptr, la, (float*)nullptr);
    hipLaunchKernelGGL(HIP_KERNEL_NAME(transpose_kernel<0, 1>), dim3(12, 64, 8), dim3(256), 0, stream,
                       vb, vTsb, decay);
    hipLaunchKernelGGL(pmat_kernel, dim3(64, 8), dim3(256), 0, stream, outb, decay, P);
    hipLaunchKernelGGL(scan_kernel, dim3(24, 8), dim3(256), 0, stream,
                       outb, oTs, vTsb, P, readsb, decay);
    hipLaunchKernelGGL(HIP_KERNEL_NAME(gemm_kernel<1>), dim3(6, 256), dim3(256), 0, stream,
                       readsb, w_rd, 768, 768, (bf16s*)nullptr,
                       x, outb, la, (float*)d_out);
}

// Round 3
// 1257.003 us; speedup vs baseline: 1.4982x; 1.4982x over previous
//
#include <hip/hip_runtime.h>
#include <stdint.h>

// ----------------------------------------------------------------------------
// HebbianLayer on MI355X (gfx950).
// B=8, T=4096, D=768, d_inner=1536, reference CHUNK=64.
// Round 3: scan re-chunked to C=1024 (exact — decay algebra is chunk-size
// independent). Sequential scan becomes 3 parallel GEMM kernels:
//   wstate: W_j states via per-tile 4-step MFMA recurrence (W in AGPRs)
//   pmat:   P'[c,c'] = (r.k) * gamma^(c-1024) * (c>c'), lower-tri tiles only
//   reads:  gamma^c * (r @ W_j^T) + P' @ v'^T   (fused two-phase GEMM)
// Workspace: 312.4 MB with liveness overlays (guard returns clean if short).
// ----------------------------------------------------------------------------

typedef short bf16s;                                            // raw bf16 bits
typedef __attribute__((ext_vector_type(8))) short short8;       // 4 VGPR mfma frag
typedef __attribute__((ext_vector_type(4))) float f32x4;        // mfma acc

#define DEVINL __device__ __forceinline__

DEVINL float bf2f(short s) {
    union { unsigned u; float f; } v; v.u = ((unsigned)(unsigned short)s) << 16; return v.f;
}
DEVINL short f2bf(float f) {
    union { float f; unsigned u; } v; v.f = f;
    unsigned r = v.u + 0x7fffu + ((v.u >> 16) & 1u);            // RNE
    return (short)(r >> 16);
}

// async global->LDS, 16B per lane. LDS dest must be wave-uniform.
DEVINL void glds16(void* lds, const void* g) {
    __builtin_amdgcn_global_load_lds(
        (const __attribute__((address_space(1))) void*)g,
        (__attribute__((address_space(3))) void*)lds, 16, 0, 0);
}

// Stage a 128-row x 64-col bf16 tile. g must be pre-offset by
// sr*gstride + sf*8 where sr=tid>>3, sf=(tid&7)^(sr&7) (XOR slot swizzle).
DEVINL void stage128(bf16s* lds, const bf16s* g, long gstride, int wave) {
#pragma unroll
    for (int p = 0; p < 4; ++p)
        glds16(lds + p * 2048 + wave * 512, g + (long)p * 32 * gstride);
}

// Read an A/B fragment from a swizzled 64-col tile.
DEVINL short8 fragr(const bf16s* t, int row, int kk, int q) {
    int f = kk * 4 + q;
    return *(const short8*)(t + row * 64 + ((f ^ (row & 7)) * 8));
}

#define MFMA(a, b, c) __builtin_amdgcn_mfma_f32_16x16x32_bf16((a), (b), (c), 0, 0, 0)

// ---------------------------------------------------------------------------
// K0: weight casts (fp32 -> bf16). w_pg = [proj_w ; gate_w] rows (3072x768).
// ---------------------------------------------------------------------------
__global__ __launch_bounds__(256) void cast_w_kernel(
    const float* __restrict__ proj, const float* __restrict__ gate,
    const float* __restrict__ op, const float* __restrict__ wr, const float* __restrict__ rd,
    bf16s* __restrict__ w_pg, bf16s* __restrict__ w_op, bf16s* __restrict__ w_wr,
    bf16s* __restrict__ w_rd) {
    long i = (long)blockIdx.x * 256 + threadIdx.x;
    if (i < 1179648)        w_pg[i] = f2bf(proj[i]);
    else if (i < 2359296)   w_pg[i] = f2bf(gate[i - 1179648]);
    else if (i < 3538944)   w_op[i - 2359296] = f2bf(op[i - 2359296]);
    else if (i < 4128768)   w_wr[i - 3538944] = f2bf(wr[i - 3538944]);
    else if (i < 4718592)   w_rd[i - 4128768] = f2bf(rd[i - 4128768]);
}

// ---------------------------------------------------------------------------
// K1: RMSNorm + cast. One block per row (768 elems).
// ---------------------------------------------------------------------------
__global__ __launch_bounds__(256) void rmsnorm_kernel(
    const float* __restrict__ x, const float* __restrict__ w, bf16s* __restrict__ xn) {
    long row = blockIdx.x;
    const float* xr = x + row * 768;
    int tid = threadIdx.x;
    float v0 = xr[tid], v1 = xr[tid + 256], v2 = xr[tid + 512];
    float ss = v0 * v0 + v1 * v1 + v2 * v2;
#pragma unroll
    for (int off = 32; off; off >>= 1) ss += __shfl_down(ss, off);
    __shared__ float p[4];
    if ((tid & 63) == 0) p[tid >> 6] = ss;
    __syncthreads();
    float tot = p[0] + p[1] + p[2] + p[3];
    float s = rsqrtf(tot * (1.0f / 768.0f) + 1e-5f);
    bf16s* o = xn + row * 768;
    o[tid]       = f2bf(v0 * s * w[tid]);
    o[tid + 256] = f2bf(v1 * s * w[tid + 256]);
    o[tid + 512] = f2bf(v2 * s * w[tid + 512]);
}

// ---------------------------------------------------------------------------
// GEMM: C[M,N] = A[M,K] @ B[N,K]^T. 128x128 tile, BK=64, 4 waves 2x2.
// MODE 0: store bf16.   MODE 1: d_out = x + bf2f(outres) + exp(la)*acc (f32).
// ---------------------------------------------------------------------------
template <int MODE>
__global__ __launch_bounds__(256, 2) void gemm_kernel(
    const bf16s* __restrict__ A, const bf16s* __restrict__ B, int K, int N,
    bf16s* __restrict__ Cb, const float* __restrict__ xres,
    const bf16s* __restrict__ outres, const float* __restrict__ p_la,
    float* __restrict__ Cout) {
    __shared__ bf16s sA[128 * 64];
    __shared__ bf16s sB[128 * 64];
    const int tid = threadIdx.x;
    const int wave = tid >> 6, lane = tid & 63;
    const int wm = wave >> 1, wn = wave & 1;
    const int ln15 = lane & 15, q = lane >> 4;
    const long m0 = (long)blockIdx.y * 128, n0 = (long)blockIdx.x * 128;
    const int sr = tid >> 3;
    const int sf = (tid & 7) ^ (sr & 7);
    const bf16s* gA = A + (m0 + sr) * K + sf * 8;
    const bf16s* gB = B + (n0 + sr) * K + sf * 8;
    f32x4 acc[4][4] = {};
    const int nkt = K >> 6;
    for (int kt = 0; kt < nkt; ++kt) {
        __syncthreads();
        stage128(sA, gA, K, wave);
        stage128(sB, gB, K, wave);
        gA += 64; gB += 64;
        asm volatile("s_waitcnt vmcnt(0)" ::: "memory");
        __syncthreads();
#pragma unroll
        for (int kk = 0; kk < 2; ++kk) {
            short8 af[4], bf_[4];
#pragma unroll
            for (int i = 0; i < 4; ++i) af[i] = fragr(sA, wm * 64 + i * 16 + ln15, kk, q);
#pragma unroll
            for (int j = 0; j < 4; ++j) bf_[j] = fragr(sB, wn * 64 + j * 16 + ln15, kk, q);
#pragma unroll
            for (int i = 0; i < 4; ++i)
#pragma unroll
                for (int j = 0; j < 4; ++j) acc[i][j] = MFMA(af[i], bf_[j], acc[i][j]);
        }
    }
    float alpha = 0.f;
    if (MODE == 1) alpha = __expf(p_la[0]);
#pragma unroll
    for (int i = 0; i < 4; ++i)
#pragma unroll
        for (int j = 0; j < 4; ++j) {
            long mb = m0 + wm * 64 + i * 16 + q * 4;
            long nc = n0 + wn * 64 + j * 16 + ln15;
#pragma unroll
            for (int e = 0; e < 4; ++e) {
                long m = mb + e;
                float v = acc[i][j][e];
                if (MODE == 0) {
                    Cb[m * N + nc] = f2bf(v);
                } else {
                    long idx = m * 768 + nc;
                    Cout[idx] = xres[idx] + bf2f(outres[idx]) + alpha * v;
                }
            }
        }
}

// ---------------------------------------------------------------------------
// K3: depthwise causal conv(4) + bias + SiLU, gated by SiLU(gate).
// Halved over M at a batch boundary, so tl = l & 4095 stays valid.
// ---------------------------------------------------------------------------
__global__ __launch_bounds__(192) void conv_kernel(
    const bf16s* __restrict__ pg, const float* __restrict__ cw,
    const float* __restrict__ cb, bf16s* __restrict__ vg) {
    long l = blockIdx.x;
    int e0 = threadIdx.x * 8;
    int tl = (int)(l & 4095);
    const bf16s* base = pg + l * 3072;
    float v[8];
#pragma unroll
    for (int i = 0; i < 8; ++i) v[i] = cb[e0 + i];
#pragma unroll
    for (int j = 0; j < 4; ++j) {
        int dt = j - 3;
        if (tl + dt >= 0) {
            short8 s8 = *(const short8*)(base + (long)dt * 3072 + e0);
#pragma unroll
            for (int i = 0; i < 8; ++i) v[i] += bf2f(s8[i]) * cw[(e0 + i) * 4 + j];
        }
    }
    short8 g8 = *(const short8*)(base + 1536 + e0);
    short8 o;
#pragma unroll
    for (int i = 0; i < 8; ++i) {
        float vv = v[i];
        float sv = vv / (1.0f + __expf(-vv));
        float gg = bf2f(g8[i]);
        float sg = gg / (1.0f + __expf(-gg));
        o[i] = f2bf(sv * sg);
    }
    *(short8*)(vg + l * 1536 + e0) = o;
}

// ---------------------------------------------------------------------------
// K5: transpose [b][t][e] -> [b][e][t], optional shift (t -> t-1, zero fill)
// and optional gw scale gamma^(1023 - t%1024). bf16 -> bf16.
// ---------------------------------------------------------------------------
template <int SHIFT, int GW>
__global__ __launch_bounds__(256) void transpose_kernel(
    const bf16s* __restrict__ src, bf16s* __restrict__ dst,
    const float* __restrict__ p_decay) {
    int b = blockIdx.z;
    long t0 = (long)blockIdx.y * 64, e0 = (long)blockIdx.x * 64;
    __shared__ bf16s tile[64][72];
    int tid = threadIdx.x;
    int r = tid >> 2, cs = (tid & 3) * 16;
    long tsrc = t0 + r - SHIFT;
    if (tsrc >= 0) {
        const bf16s* s = src + ((long)b * 4096 + tsrc) * 768 + e0 + cs;
        short8 v0 = *(const short8*)s;
        short8 v1 = *(const short8*)(s + 8);
        if (GW) {
            float gm = 1.0f / (1.0f + __expf(-p_decay[0]));
            float gwf = exp2f(__log2f(gm) * (float)(1023 - (int)(tsrc & 1023)));
#pragma unroll
            for (int i = 0; i < 8; ++i) {
                tile[r][cs + i]     = f2bf(bf2f(v0[i]) * gwf);
                tile[r][cs + 8 + i] = f2bf(bf2f(v1[i]) * gwf);
            }
        } else {
#pragma unroll
            for (int i = 0; i < 8; ++i) {
                tile[r][cs + i]     = v0[i];
                tile[r][cs + 8 + i] = v1[i];
            }
        }
    } else {
#pragma unroll
        for (int i = 0; i < 16; ++i) tile[r][cs + i] = 0;
    }
    __syncthreads();
    int er = tid >> 2, ts = (tid & 3) * 16;
    short8 a, bb;
#pragma unroll
    for (int i = 0; i < 8; ++i) a[i] = tile[ts + i][er];
#pragma unroll
    for (int i = 0; i < 8; ++i) bb[i] = tile[ts + 8 + i][er];
    bf16s* d = dst + ((long)b * 768 + e0 + er) * 4096 + t0 + ts;
    *(short8*)d = a;
    *(short8*)(d + 8) = bb;
}

// ---------------------------------------------------------------------------
// K6: W-state kernel. C=1024, Nc=4. Block owns one 128x128 tile of W[vd][kd]
// for one b. Sequentially over 4 chunks: store Wst[b][j] = acc (bf16), then
// acc = gamma^1024 * acc + U_j accumulated by MFMA over the chunk (K=1024).
//   U_j[vd,kd] = sum_c v'[c,vd] * k[c,kd];  A = vTs[b][vd][t], B = oTs[b][kd][t].
// ---------------------------------------------------------------------------
__global__ __launch_bounds__(256, 2) void wstate_kernel(
    const bf16s* __restrict__ vTs, const bf16s* __restrict__ oTs,
    bf16s* __restrict__ Wst, const float* __restrict__ p_decay) {
    __shared__ bf16s sA[128 * 64];
    __shared__ bf16s sB[128 * 64];
    const int b = blockIdx.y;
    const int ti = blockIdx.x % 6, tj = blockIdx.x / 6;
    const int tid = threadIdx.x;
    const int wave = tid >> 6, lane = tid & 63;
    const int wm = wave >> 1, wn = wave & 1;
    const int ln15 = lane & 15, q = lane >> 4;
    const int sr = tid >> 3;
    const int sf = (tid & 7) ^ (sr & 7);
    const bf16s* gA = vTs + ((long)b * 768 + ti * 128 + sr) * 4096 + sf * 8;
    const bf16s* gB = oTs + ((long)b * 768 + tj * 128 + sr) * 4096 + sf * 8;
    const float gm = 1.0f / (1.0f + __expf(-p_decay[0]));
    const float gC = exp2f(__log2f(gm) * 1024.0f);
    f32x4 acc[4][4] = {};
    for (int jc = 0; jc < 4; ++jc) {
        // store W state for chunk jc (before accumulating chunk jc's update)
        bf16s* Wj = Wst + ((long)(b * 4 + jc)) * 768 * 768;
#pragma unroll
        for (int i = 0; i < 4; ++i)
#pragma unroll
            for (int jj = 0; jj < 4; ++jj) {
                long mb = ti * 128 + wm * 64 + i * 16 + q * 4;
                long nc = tj * 128 + wn * 64 + jj * 16 + ln15;
#pragma unroll
                for (int e = 0; e < 4; ++e) {
                    Wj[(mb + e) * 768 + nc] = f2bf(acc[i][jj][e]);
                    acc[i][jj][e] *= gC;
                }
            }
        for (int kt = 0; kt < 16; ++kt) {
            __syncthreads();
            stage128(sA, gA, 4096, wave);
            stage128(sB, gB, 4096, wave);
            gA += 64; gB += 64;
            asm volatile("s_waitcnt vmcnt(0)" ::: "memory");
            __syncthreads();
#pragma unroll
            for (int kk = 0; kk < 2; ++kk) {
                short8 af[4], bf_[4];
#pragma unroll
                for (int i = 0; i < 4; ++i) af[i] = fragr(sA, wm * 64 + i * 16 + ln15, kk, q);
#pragma unroll
                for (int j = 0; j < 4; ++j) bf_[j] = fragr(sB, wn * 64 + j * 16 + ln15, kk, q);
#pragma unroll
                for (int i = 0; i < 4; ++i)
#pragma unroll
                    for (int j = 0; j < 4; ++j) acc[i][j] = MFMA(af[i], bf_[j], acc[i][j]);
            }
        }
    }
}

// ---------------------------------------------------------------------------
// K7: P'[b,j][c][c'] = bf16( (r_c . k_c') * gamma^(c-1024) * (c>c') ).
// Lower-triangular 128x128 tiles only (cj <= ci); others never read.
// k = out shifted by one t (zero row at global t=-1, i.e. j==0,cj==0,row 0).
// ---------------------------------------------------------------------------
__global__ __launch_bounds__(256, 2) void pmat_kernel(
    const bf16s* __restrict__ outb, bf16s* __restrict__ P,
    const float* __restrict__ p_decay) {
    const int ci = blockIdx.x >> 3, cj = blockIdx.x & 7;
    if (cj > ci) return;
    const int j = blockIdx.y, b = blockIdx.z;
    const bool fix = (j == 0 && cj == 0);
    __shared__ bf16s sA[128 * 64];
    __shared__ bf16s sB[128 * 64];
    const int tid = threadIdx.x;
    const int wave = tid >> 6, lane = tid & 63;
    const int wm = wave >> 1, wn = wave & 1;
    const int ln15 = lane & 15, q = lane >> 4;
    const int sr = tid >> 3;
    const int sf = (tid & 7) ^ (sr & 7);
    const bf16s* gA = outb + ((long)b * 4096 + j * 1024 + ci * 128 + sr) * 768 + sf * 8;
    const bf16s* gB = outb + ((long)b * 4096 + j * 1024 + cj * 128 + sr - 1) * 768 + sf * 8;
    f32x4 acc[4][4] = {};
    for (int kt = 0; kt < 12; ++kt) {
        __syncthreads();
        stage128(sA, gA, 768, wave);
        stage128(sB, gB, 768, wave);
        gA += 64; gB += 64;
        asm volatile("s_waitcnt vmcnt(0)" ::: "memory");
        __syncthreads();
        if (fix) {                         // B row 0 is global t=-1 -> zero
            if (tid < 8) { short8 zz = {0,0,0,0,0,0,0,0}; ((short8*)sB)[tid] = zz; }
            __syncthreads();
        }
#pragma unroll
        for (int kk = 0; kk < 2; ++kk) {
            short8 af[4], bf_[4];
#pragma unroll
            for (int i = 0; i < 4; ++i) af[i] = fragr(sA, wm * 64 + i * 16 + ln15, kk, q);
#pragma unroll
            for (int jj = 0; jj < 4; ++jj) bf_[jj] = fragr(sB, wn * 64 + jj * 16 + ln15, kk, q);
#pragma unroll
            for (int i = 0; i < 4; ++i)
#pragma unroll
                for (int jj = 0; jj < 4; ++jj) acc[i][jj] = MFMA(af[i], bf_[jj], acc[i][jj]);
        }
    }
    const float lg = __log2f(1.0f / (1.0f + __expf(-p_decay[0])));
    bf16s* Pb = P + ((long)(b * 4 + j) << 20);
#pragma unroll
    for (int i = 0; i < 4; ++i)
#pragma unroll
        for (int jj = 0; jj < 4; ++jj) {
            int cb_ = ci * 128 + wm * 64 + i * 16 + q * 4;
            int cp  = cj * 128 + wn * 64 + jj * 16 + ln15;
#pragma unroll
            for (int e = 0; e < 4; ++e) {
                int c = cb_ + e;
                float val = (c > cp) ? acc[i][jj][e] * exp2f(lg * (float)(c - 1024)) : 0.0f;
                Pb[(long)c * 1024 + cp] = f2bf(val);
            }
        }
}

// ---------------------------------------------------------------------------
// K8: reads[c, vd] = gamma^(c%1024) * (r_c @ Wst[b,j]^T)   [skip for j==0]
//                  + P'[b,j] @ vTs^T                        (K limited to c'<=c)
// Output tile 128(c) x 128(vd). Two K-phases into one accumulator.
// ---------------------------------------------------------------------------
__global__ __launch_bounds__(256, 2) void reads_kernel(
    const bf16s* __restrict__ outb, const bf16s* __restrict__ Wst,
    const bf16s* __restrict__ Pm, const bf16s* __restrict__ vTs,
    bf16s* __restrict__ readsb, const float* __restrict__ p_decay) {
    const int ci = blockIdx.x & 7, vi = blockIdx.x >> 3;
    const int j = blockIdx.y, b = blockIdx.z;
    __shared__ bf16s sA[128 * 64];
    __shared__ bf16s sB[128 * 64];
    const int tid = threadIdx.x;
    const int wave = tid >> 6, lane = tid & 63;
    const int wm = wave >> 1, wn = wave & 1;
    const int ln15 = lane & 15, q = lane >> 4;
    const int sr = tid >> 3;
    const int sf = (tid & 7) ^ (sr & 7);
    const float lg = __log2f(1.0f / (1.0f + __expf(-p_decay[0])));
    f32x4 acc[4][4] = {};
    if (j > 0) {
        // inter: A = r rows (outb), B = Wst[b][j][vd][kd]
        const bf16s* gA = outb + ((long)b * 4096 + j * 1024 + ci * 128 + sr) * 768 + sf * 8;
        const bf16s* gB = Wst + ((long)(b * 4 + j) * 768 + vi * 128 + sr) * 768 + sf * 8;
        for (int kt = 0; kt < 12; ++kt) {
            __syncthreads();
            stage128(sA, gA, 768, wave);
            stage128(sB, gB, 768, wave);
            gA += 64; gB += 64;
            asm volatile("s_waitcnt vmcnt(0)" ::: "memory");
            __syncthreads();
#pragma unroll
            for (int kk = 0; kk < 2; ++kk) {
                short8 af[4], bf_[4];
#pragma unroll
                for (int i = 0; i < 4; ++i) af[i] = fragr(sA, wm * 64 + i * 16 + ln15, kk, q);
#pragma unroll
                for (int jj = 0; jj < 4; ++jj) bf_[jj] = fragr(sB, wn * 64 + jj * 16 + ln15, kk, q);
#pragma unroll
                for (int i = 0; i < 4; ++i)
#pragma unroll
                    for (int jj = 0; jj < 4; ++jj) acc[i][jj] = MFMA(af[i], bf_[jj], acc[i][jj]);
            }
        }
        // scale by gp = gamma^(c mod 1024)
#pragma unroll
        for (int i = 0; i < 4; ++i) {
            int cb_ = ci * 128 + wm * 64 + i * 16 + q * 4;
#pragma unroll
            for (int e = 0; e < 4; ++e) {
                float s = exp2f(lg * (float)(cb_ + e));
#pragma unroll
                for (int jj = 0; jj < 4; ++jj) acc[i][jj][e] *= s;
            }
        }
    }
    // intra: A = P'[b,j] rows c (stride 1024), B = vTs rows vd (stride 4096)
    {
        const bf16s* gA = Pm + ((long)(b * 4 + j) << 20) + (long)(ci * 128 + sr) * 1024 + sf * 8;
        const bf16s* gB = vTs + ((long)b * 768 + vi * 128 + sr) * 4096 + j * 1024 + sf * 8;
        const int nkt = 2 * (ci + 1);
        for (int kt = 0; kt < nkt; ++kt) {
            __syncthreads();
            stage128(sA, gA, 1024, wave);
            stage128(sB, gB, 4096, wave);
            gA += 64; gB += 64;
            asm volatile("s_waitcnt vmcnt(0)" ::: "memory");
            __syncthreads();
#pragma unroll
            for (int kk = 0; kk < 2; ++kk) {
                short8 af[4], bf_[4];
#pragma unroll
                for (int i = 0; i < 4; ++i) af[i] = fragr(sA, wm * 64 + i * 16 + ln15, kk, q);
#pragma unroll
                for (int jj = 0; jj < 4; ++jj) bf_[jj] = fragr(sB, wn * 64 + jj * 16 + ln15, kk, q);
#pragma unroll
                for (int i = 0; i < 4; ++i)
#pragma unroll
                    for (int jj = 0; jj < 4; ++jj) acc[i][jj] = MFMA(af[i], bf_[jj], acc[i][jj]);
            }
        }
    }
#pragma unroll
    for (int i = 0; i < 4; ++i)
#pragma unroll
        for (int jj = 0; jj < 4; ++jj) {
            long tb = (long)j * 1024 + ci * 128 + wm * 64 + i * 16 + q * 4;
            long nc = vi * 128 + wn * 64 + jj * 16 + ln15;
#pragma unroll
            for (int e = 0; e < 4; ++e)
                readsb[((long)b * 4096 + tb + e) * 768 + nc] = f2bf(acc[i][jj][e]);
        }
}

// ---------------------------------------------------------------------------
extern "C" void kernel_launch(void* const* d_in, const int* in_sizes, int n_in,
                              void* d_out, int out_size, void* d_ws, size_t ws_size,
                              hipStream_t stream) {
    (void)in_sizes; (void)n_in; (void)out_size;
    const float* x      = (const float*)d_in[0];
    const float* norm_w = (const float*)d_in[1];
    const float* proj_w = (const float*)d_in[2];
    const float* gate_w = (const float*)d_in[3];
    const float* conv_w = (const float*)d_in[4];
    const float* conv_b = (const float*)d_in[5];
    const float* op_w   = (const float*)d_in[6];
    const float* wr_w   = (const float*)d_in[7];
    const float* rd_w   = (const float*)d_in[8];
    const float* decay  = (const float*)d_in[9];
    const float* la     = (const float*)d_in[10];

    // -------- workspace layout (liveness overlays), ~312.4 MB total --------
    char* ws = (char*)d_ws;
    size_t off = 0;
    auto alloc = [&](size_t bytes) { void* p = ws + off; off += (bytes + 255) & ~(size_t)255; return p; };
    bf16s* w_pg = (bf16s*)alloc(3072l * 768 * 2);          // 4.7 MB
    bf16s* w_op = (bf16s*)alloc(768l * 1536 * 2);          // 2.4 MB
    bf16s* w_wr = (bf16s*)alloc(768l * 768 * 2);           // 1.2 MB
    bf16s* w_rd = (bf16s*)alloc(768l * 768 * 2);           // 1.2 MB
    bf16s* RA   = (bf16s*)alloc(32768l * 768 * 2);         // 50.3 MB: xn | vTs
    bf16s* RB   = (bf16s*)alloc(2 * 32768l * 768 * 2);     // 100.7 MB: pg | vb+oTs | P'
    bf16s* RC   = (bf16s*)alloc(2 * 32768l * 768 * 2);     // 100.7 MB: vg | Wst+reads
    bf16s* RE   = (bf16s*)alloc(32768l * 768 * 2);         // 50.3 MB: outb
    if (ws_size < off) return;   // diagnostic guard: fail clean, don't fault

    bf16s* xn    = RA;
    bf16s* vTs   = RA;
    bf16s* pgH   = RB;                     // 16384 x 3072 (one M-half)
    bf16s* vb    = RB;                     // [0:50.3 MB]
    bf16s* oTs   = RB + 25165824;          // [50.3:100.7 MB]
    bf16s* Pm    = RB;                     // 67.1 MB (after vb & oTs are dead)
    bf16s* vg    = RC;                     // 32768 x 1536
    bf16s* Wst   = RC;                     // 37.75 MB (after vg dead)
    bf16s* readsb= RC + 18874368;          // [37.75:88.1 MB]
    bf16s* outb  = RE;

    hipLaunchKernelGGL(cast_w_kernel, dim3(18432), dim3(256), 0, stream,
                       proj_w, gate_w, op_w, wr_w, rd_w, w_pg, w_op, w_wr, w_rd);
    hipLaunchKernelGGL(rmsnorm_kernel, dim3(32768), dim3(256), 0, stream, x, norm_w, xn);
    // proj+gate GEMM + conv, split at the batch-4 boundary (no conv halo)
    for (int h = 0; h < 2; ++h) {
        hipLaunchKernelGGL(HIP_KERNEL_NAME(gemm_kernel<0>), dim3(24, 128), dim3(256), 0, stream,
                           xn + (long)h * 16384 * 768, w_pg, 768, 3072, pgH,
                           (const float*)nullptr, (const bf16s*)nullptr, la, (float*)nullptr);
        hipLaunchKernelGGL(conv_kernel, dim3(16384), dim3(192), 0, stream,
                           pgH, conv_w, conv_b, vg + (long)h * 16384 * 1536);
    }
    hipLaunchKernelGGL(HIP_KERNEL_NAME(gemm_kernel<0>), dim3(6, 256), dim3(256), 0, stream,
                       vg, w_op, 1536, 768, outb,
                       (const float*)nullptr, (const bf16s*)nullptr, la, (float*)nullptr);
    hipLaunchKernelGGL(HIP_KERNEL_NAME(gemm_kernel<0>), dim3(6, 256), dim3(256), 0, stream,
                       outb, w_wr, 768, 768, vb,
                       (const float*)nullptr, (const bf16s*)nullptr, la, (float*)nullptr);
    hipLaunchKernelGGL(HIP_KERNEL_NAME(transpose_kernel<1, 0>), dim3(12, 64, 8), dim3(256), 0, stream,
                       outb, oTs, decay);
    hipLaunchKernelGGL(HIP_KERNEL_NAME(transpose_kernel<0, 1>), dim3(12, 64, 8), dim3(256), 0, stream,
                       vb, vTs, decay);
    hipLaunchKernelGGL(wstate_kernel, dim3(36, 8), dim3(256), 0, stream,
                       vTs, oTs, Wst, decay);
    hipLaunchKernelGGL(pmat_kernel, dim3(64, 4, 8), dim3(256), 0, stream,
                       outb, Pm, decay);          // clobbers vb+oTs (both dead)
    hipLaunchKernelGGL(reads_kernel, dim3(48, 4, 8), dim3(256), 0, stream,
                       outb, Wst, Pm, vTs, readsb, decay);
    hipLaunchKernelGGL(HIP_KERNEL_NAME(gemm_kernel<1>), dim3(6, 256), dim3(256), 0, stream,
                       readsb, w_rd, 768, 768, (bf16s*)nullptr,
                       x, outb, la, (float*)d_out);
}

// Round 4
// 971.801 us; speedup vs baseline: 1.9379x; 1.2935x over previous
//
#include <hip/hip_runtime.h>
#include <stdint.h>

// ----------------------------------------------------------------------------
// HebbianLayer on MI355X (gfx950).
// B=8, T=4096, D=768, d_inner=1536, reference CHUNK=64.
// R3: scan re-chunked to C=1024 -> 3 parallel GEMM kernels (wstate/pmat/reads).
// R4: conv rewritten as sliding-window streaming kernel (weights loaded once
// per thread, 3-row history in registers, 1-iter prefetch) — old version was
// issue-bound at 7x off the HBM roofline (46 VMEM instr per output row).
// ----------------------------------------------------------------------------

typedef short bf16s;                                            // raw bf16 bits
typedef __attribute__((ext_vector_type(8))) short short8;       // 4 VGPR mfma frag
typedef __attribute__((ext_vector_type(4))) float f32x4;        // mfma acc

#define DEVINL __device__ __forceinline__

DEVINL float bf2f(short s) {
    union { unsigned u; float f; } v; v.u = ((unsigned)(unsigned short)s) << 16; return v.f;
}
DEVINL short f2bf(float f) {
    union { float f; unsigned u; } v; v.f = f;
    unsigned r = v.u + 0x7fffu + ((v.u >> 16) & 1u);            // RNE
    return (short)(r >> 16);
}

// async global->LDS, 16B per lane. LDS dest must be wave-uniform.
DEVINL void glds16(void* lds, const void* g) {
    __builtin_amdgcn_global_load_lds(
        (const __attribute__((address_space(1))) void*)g,
        (__attribute__((address_space(3))) void*)lds, 16, 0, 0);
}

// Stage a 128-row x 64-col bf16 tile. g must be pre-offset by
// sr*gstride + sf*8 where sr=tid>>3, sf=(tid&7)^(sr&7) (XOR slot swizzle).
DEVINL void stage128(bf16s* lds, const bf16s* g, long gstride, int wave) {
#pragma unroll
    for (int p = 0; p < 4; ++p)
        glds16(lds + p * 2048 + wave * 512, g + (long)p * 32 * gstride);
}

// Read an A/B fragment from a swizzled 64-col tile.
DEVINL short8 fragr(const bf16s* t, int row, int kk, int q) {
    int f = kk * 4 + q;
    return *(const short8*)(t + row * 64 + ((f ^ (row & 7)) * 8));
}

#define MFMA(a, b, c) __builtin_amdgcn_mfma_f32_16x16x32_bf16((a), (b), (c), 0, 0, 0)

// ---------------------------------------------------------------------------
// K0: weight casts (fp32 -> bf16). w_pg = [proj_w ; gate_w] rows (3072x768).
// ---------------------------------------------------------------------------
__global__ __launch_bounds__(256) void cast_w_kernel(
    const float* __restrict__ proj, const float* __restrict__ gate,
    const float* __restrict__ op, const float* __restrict__ wr, const float* __restrict__ rd,
    bf16s* __restrict__ w_pg, bf16s* __restrict__ w_op, bf16s* __restrict__ w_wr,
    bf16s* __restrict__ w_rd) {
    long i = (long)blockIdx.x * 256 + threadIdx.x;
    if (i < 1179648)        w_pg[i] = f2bf(proj[i]);
    else if (i < 2359296)   w_pg[i] = f2bf(gate[i - 1179648]);
    else if (i < 3538944)   w_op[i - 2359296] = f2bf(op[i - 2359296]);
    else if (i < 4128768)   w_wr[i - 3538944] = f2bf(wr[i - 3538944]);
    else if (i < 4718592)   w_rd[i - 4128768] = f2bf(rd[i - 4128768]);
}

// ---------------------------------------------------------------------------
// K1: RMSNorm + cast. One block per row (768 elems).
// ---------------------------------------------------------------------------
__global__ __launch_bounds__(256) void rmsnorm_kernel(
    const float* __restrict__ x, const float* __restrict__ w, bf16s* __restrict__ xn) {
    long row = blockIdx.x;
    const float* xr = x + row * 768;
    int tid = threadIdx.x;
    float v0 = xr[tid], v1 = xr[tid + 256], v2 = xr[tid + 512];
    float ss = v0 * v0 + v1 * v1 + v2 * v2;
#pragma unroll
    for (int off = 32; off; off >>= 1) ss += __shfl_down(ss, off);
    __shared__ float p[4];
    if ((tid & 63) == 0) p[tid >> 6] = ss;
    __syncthreads();
    float tot = p[0] + p[1] + p[2] + p[3];
    float s = rsqrtf(tot * (1.0f / 768.0f) + 1e-5f);
    bf16s* o = xn + row * 768;
    o[tid]       = f2bf(v0 * s * w[tid]);
    o[tid + 256] = f2bf(v1 * s * w[tid + 256]);
    o[tid + 512] = f2bf(v2 * s * w[tid + 512]);
}

// ---------------------------------------------------------------------------
// GEMM: C[M,N] = A[M,K] @ B[N,K]^T. 128x128 tile, BK=64, 4 waves 2x2.
// MODE 0: store bf16.   MODE 1: d_out = x + bf2f(outres) + exp(la)*acc (f32).
// ---------------------------------------------------------------------------
template <int MODE>
__global__ __launch_bounds__(256, 2) void gemm_kernel(
    const bf16s* __restrict__ A, const bf16s* __restrict__ B, int K, int N,
    bf16s* __restrict__ Cb, const float* __restrict__ xres,
    const bf16s* __restrict__ outres, const float* __restrict__ p_la,
    float* __restrict__ Cout) {
    __shared__ bf16s sA[128 * 64];
    __shared__ bf16s sB[128 * 64];
    const int tid = threadIdx.x;
    const int wave = tid >> 6, lane = tid & 63;
    const int wm = wave >> 1, wn = wave & 1;
    const int ln15 = lane & 15, q = lane >> 4;
    const long m0 = (long)blockIdx.y * 128, n0 = (long)blockIdx.x * 128;
    const int sr = tid >> 3;
    const int sf = (tid & 7) ^ (sr & 7);
    const bf16s* gA = A + (m0 + sr) * K + sf * 8;
    const bf16s* gB = B + (n0 + sr) * K + sf * 8;
    f32x4 acc[4][4] = {};
    const int nkt = K >> 6;
    for (int kt = 0; kt < nkt; ++kt) {
        __syncthreads();
        stage128(sA, gA, K, wave);
        stage128(sB, gB, K, wave);
        gA += 64; gB += 64;
        asm volatile("s_waitcnt vmcnt(0)" ::: "memory");
        __syncthreads();
#pragma unroll
        for (int kk = 0; kk < 2; ++kk) {
            short8 af[4], bf_[4];
#pragma unroll
            for (int i = 0; i < 4; ++i) af[i] = fragr(sA, wm * 64 + i * 16 + ln15, kk, q);
#pragma unroll
            for (int j = 0; j < 4; ++j) bf_[j] = fragr(sB, wn * 64 + j * 16 + ln15, kk, q);
#pragma unroll
            for (int i = 0; i < 4; ++i)
#pragma unroll
                for (int j = 0; j < 4; ++j) acc[i][j] = MFMA(af[i], bf_[j], acc[i][j]);
        }
    }
    float alpha = 0.f;
    if (MODE == 1) alpha = __expf(p_la[0]);
#pragma unroll
    for (int i = 0; i < 4; ++i)
#pragma unroll
        for (int j = 0; j < 4; ++j) {
            long mb = m0 + wm * 64 + i * 16 + q * 4;
            long nc = n0 + wn * 64 + j * 16 + ln15;
#pragma unroll
            for (int e = 0; e < 4; ++e) {
                long m = mb + e;
                float v = acc[i][j][e];
                if (MODE == 0) {
                    Cb[m * N + nc] = f2bf(v);
                } else {
                    long idx = m * 768 + nc;
                    Cout[idx] = xres[idx] + bf2f(outres[idx]) + alpha * v;
                }
            }
        }
}

// ---------------------------------------------------------------------------
// K3: depthwise causal conv(4) + bias + SiLU, gated by SiLU(gate).
// Sliding-window streaming version: thread owns 8 channels x 16 time steps.
// Weights/bias in registers (loaded once), 3-row causal history in registers,
// one-iteration load-ahead prefetch. Launched per 16384-row half; halves are
// whole sequences so tl0==0 detects sequence starts.
// ---------------------------------------------------------------------------
__global__ __launch_bounds__(192) void conv_kernel(
    const bf16s* __restrict__ pg, const float* __restrict__ cw,
    const float* __restrict__ cb, bf16s* __restrict__ vg) {
    const int e0 = threadIdx.x * 8;
    const long l0 = (long)blockIdx.x * 16;
    float w0[8], w1[8], w2[8], w3[8], bias[8];
#pragma unroll
    for (int i = 0; i < 8; ++i) {
        const float* wc = cw + (e0 + i) * 4;
        w0[i] = wc[0]; w1[i] = wc[1]; w2[i] = wc[2]; w3[i] = wc[3];
        bias[i] = cb[e0 + i];
    }
    const bf16s* base = pg + l0 * 3072 + e0;
    short8 h0, h1, h2;
    if ((l0 & 4095) == 0) {
        short8 z = {0, 0, 0, 0, 0, 0, 0, 0};
        h0 = z; h1 = z; h2 = z;
    } else {
        h0 = *(const short8*)(base - 3 * 3072);
        h1 = *(const short8*)(base - 2 * 3072);
        h2 = *(const short8*)(base - 1 * 3072);
    }
    short8 cur = *(const short8*)base;
    short8 g8  = *(const short8*)(base + 1536);
    bf16s* out = vg + l0 * 1536 + e0;
#pragma unroll 4
    for (int t = 0; t < 16; ++t) {
        short8 ncur, ng;
        if (t < 15) {                       // prefetch next row
            ncur = *(const short8*)(base + 3072);
            ng   = *(const short8*)(base + 3072 + 1536);
        }
        short8 o;
#pragma unroll
        for (int i = 0; i < 8; ++i) {
            float vv = bias[i] + bf2f(h0[i]) * w0[i] + bf2f(h1[i]) * w1[i]
                     + bf2f(h2[i]) * w2[i] + bf2f(cur[i]) * w3[i];
            float sv = vv / (1.0f + __expf(-vv));
            float gg = bf2f(g8[i]);
            o[i] = f2bf(sv * (gg / (1.0f + __expf(-gg))));
        }
        *(short8*)out = o;
        h0 = h1; h1 = h2; h2 = cur;
        cur = ncur; g8 = ng;
        base += 3072; out += 1536;
    }
}

// ---------------------------------------------------------------------------
// K5: transpose [b][t][e] -> [b][e][t], optional shift (t -> t-1, zero fill)
// and optional gw scale gamma^(1023 - t%1024). bf16 -> bf16.
// ---------------------------------------------------------------------------
template <int SHIFT, int GW>
__global__ __launch_bounds__(256) void transpose_kernel(
    const bf16s* __restrict__ src, bf16s* __restrict__ dst,
    const float* __restrict__ p_decay) {
    int b = blockIdx.z;
    long t0 = (long)blockIdx.y * 64, e0 = (long)blockIdx.x * 64;
    __shared__ bf16s tile[64][72];
    int tid = threadIdx.x;
    int r = tid >> 2, cs = (tid & 3) * 16;
    long tsrc = t0 + r - SHIFT;
    if (tsrc >= 0) {
        const bf16s* s = src + ((long)b * 4096 + tsrc) * 768 + e0 + cs;
        short8 v0 = *(const short8*)s;
        short8 v1 = *(const short8*)(s + 8);
        if (GW) {
            float gm = 1.0f / (1.0f + __expf(-p_decay[0]));
            float gwf = exp2f(__log2f(gm) * (float)(1023 - (int)(tsrc & 1023)));
#pragma unroll
            for (int i = 0; i < 8; ++i) {
                tile[r][cs + i]     = f2bf(bf2f(v0[i]) * gwf);
                tile[r][cs + 8 + i] = f2bf(bf2f(v1[i]) * gwf);
            }
        } else {
#pragma unroll
            for (int i = 0; i < 8; ++i) {
                tile[r][cs + i]     = v0[i];
                tile[r][cs + 8 + i] = v1[i];
            }
        }
    } else {
#pragma unroll
        for (int i = 0; i < 16; ++i) tile[r][cs + i] = 0;
    }
    __syncthreads();
    int er = tid >> 2, ts = (tid & 3) * 16;
    short8 a, bb;
#pragma unroll
    for (int i = 0; i < 8; ++i) a[i] = tile[ts + i][er];
#pragma unroll
    for (int i = 0; i < 8; ++i) bb[i] = tile[ts + 8 + i][er];
    bf16s* d = dst + ((long)b * 768 + e0 + er) * 4096 + t0 + ts;
    *(short8*)d = a;
    *(short8*)(d + 8) = bb;
}

// ---------------------------------------------------------------------------
// K6: W-state kernel. C=1024, Nc=4. Block owns one 128x128 tile of W[vd][kd]
// for one b. Sequentially over 4 chunks: store Wst[b][j] = acc (bf16), then
// acc = gamma^1024 * acc + U_j accumulated by MFMA over the chunk (K=1024).
//   U_j[vd,kd] = sum_c v'[c,vd] * k[c,kd];  A = vTs[b][vd][t], B = oTs[b][kd][t].
// ---------------------------------------------------------------------------
__global__ __launch_bounds__(256, 2) void wstate_kernel(
    const bf16s* __restrict__ vTs, const bf16s* __restrict__ oTs,
    bf16s* __restrict__ Wst, const float* __restrict__ p_decay) {
    __shared__ bf16s sA[128 * 64];
    __shared__ bf16s sB[128 * 64];
    const int b = blockIdx.y;
    const int ti = blockIdx.x % 6, tj = blockIdx.x / 6;
    const int tid = threadIdx.x;
    const int wave = tid >> 6, lane = tid & 63;
    const int wm = wave >> 1, wn = wave & 1;
    const int ln15 = lane & 15, q = lane >> 4;
    const int sr = tid >> 3;
    const int sf = (tid & 7) ^ (sr & 7);
    const bf16s* gA = vTs + ((long)b * 768 + ti * 128 + sr) * 4096 + sf * 8;
    const bf16s* gB = oTs + ((long)b * 768 + tj * 128 + sr) * 4096 + sf * 8;
    const float gm = 1.0f / (1.0f + __expf(-p_decay[0]));
    const float gC = exp2f(__log2f(gm) * 1024.0f);
    f32x4 acc[4][4] = {};
    for (int jc = 0; jc < 4; ++jc) {
        bf16s* Wj = Wst + ((long)(b * 4 + jc)) * 768 * 768;
#pragma unroll
        for (int i = 0; i < 4; ++i)
#pragma unroll
            for (int jj = 0; jj < 4; ++jj) {
                long mb = ti * 128 + wm * 64 + i * 16 + q * 4;
                long nc = tj * 128 + wn * 64 + jj * 16 + ln15;
#pragma unroll
                for (int e = 0; e < 4; ++e) {
                    Wj[(mb + e) * 768 + nc] = f2bf(acc[i][jj][e]);
                    acc[i][jj][e] *= gC;
                }
            }
        for (int kt = 0; kt < 16; ++kt) {
            __syncthreads();
            stage128(sA, gA, 4096, wave);
            stage128(sB, gB, 4096, wave);
            gA += 64; gB += 64;
            asm volatile("s_waitcnt vmcnt(0)" ::: "memory");
            __syncthreads();
#pragma unroll
            for (int kk = 0; kk < 2; ++kk) {
                short8 af[4], bf_[4];
#pragma unroll
                for (int i = 0; i < 4; ++i) af[i] = fragr(sA, wm * 64 + i * 16 + ln15, kk, q);
#pragma unroll
                for (int j = 0; j < 4; ++j) bf_[j] = fragr(sB, wn * 64 + j * 16 + ln15, kk, q);
#pragma unroll
                for (int i = 0; i < 4; ++i)
#pragma unroll
                    for (int j = 0; j < 4; ++j) acc[i][j] = MFMA(af[i], bf_[j], acc[i][j]);
            }
        }
    }
}

// ---------------------------------------------------------------------------
// K7: P'[b,j][c][c'] = bf16( (r_c . k_c') * gamma^(c-1024) * (c>c') ).
// Lower-triangular 128x128 tiles only (cj <= ci); others never read.
// k = out shifted by one t (zero row at global t=-1, i.e. j==0,cj==0,row 0).
// ---------------------------------------------------------------------------
__global__ __launch_bounds__(256, 2) void pmat_kernel(
    const bf16s* __restrict__ outb, bf16s* __restrict__ P,
    const float* __restrict__ p_decay) {
    const int ci = blockIdx.x >> 3, cj = blockIdx.x & 7;
    if (cj > ci) return;
    const int j = blockIdx.y, b = blockIdx.z;
    const bool fix = (j == 0 && cj == 0);
    __shared__ bf16s sA[128 * 64];
    __shared__ bf16s sB[128 * 64];
    const int tid = threadIdx.x;
    const int wave = tid >> 6, lane = tid & 63;
    const int wm = wave >> 1, wn = wave & 1;
    const int ln15 = lane & 15, q = lane >> 4;
    const int sr = tid >> 3;
    const int sf = (tid & 7) ^ (sr & 7);
    const bf16s* gA = outb + ((long)b * 4096 + j * 1024 + ci * 128 + sr) * 768 + sf * 8;
    const bf16s* gB = outb + ((long)b * 4096 + j * 1024 + cj * 128 + sr - 1) * 768 + sf * 8;
    f32x4 acc[4][4] = {};
    for (int kt = 0; kt < 12; ++kt) {
        __syncthreads();
        stage128(sA, gA, 768, wave);
        stage128(sB, gB, 768, wave);
        gA += 64; gB += 64;
        asm volatile("s_waitcnt vmcnt(0)" ::: "memory");
        __syncthreads();
        if (fix) {                         // B row 0 is global t=-1 -> zero
            if (tid < 8) { short8 zz = {0,0,0,0,0,0,0,0}; ((short8*)sB)[tid] = zz; }
            __syncthreads();
        }
#pragma unroll
        for (int kk = 0; kk < 2; ++kk) {
            short8 af[4], bf_[4];
#pragma unroll
            for (int i = 0; i < 4; ++i) af[i] = fragr(sA, wm * 64 + i * 16 + ln15, kk, q);
#pragma unroll
            for (int jj = 0; jj < 4; ++jj) bf_[jj] = fragr(sB, wn * 64 + jj * 16 + ln15, kk, q);
#pragma unroll
            for (int i = 0; i < 4; ++i)
#pragma unroll
                for (int jj = 0; jj < 4; ++jj) acc[i][jj] = MFMA(af[i], bf_[jj], acc[i][jj]);
        }
    }
    const float lg = __log2f(1.0f / (1.0f + __expf(-p_decay[0])));
    bf16s* Pb = P + ((long)(b * 4 + j) << 20);
#pragma unroll
    for (int i = 0; i < 4; ++i)
#pragma unroll
        for (int jj = 0; jj < 4; ++jj) {
            int cb_ = ci * 128 + wm * 64 + i * 16 + q * 4;
            int cp  = cj * 128 + wn * 64 + jj * 16 + ln15;
#pragma unroll
            for (int e = 0; e < 4; ++e) {
                int c = cb_ + e;
                float val = (c > cp) ? acc[i][jj][e] * exp2f(lg * (float)(c - 1024)) : 0.0f;
                Pb[(long)c * 1024 + cp] = f2bf(val);
            }
        }
}

// ---------------------------------------------------------------------------
// K8: reads[c, vd] = gamma^(c%1024) * (r_c @ Wst[b,j]^T)   [skip for j==0]
//                  + P'[b,j] @ vTs^T                        (K limited to c'<=c)
// Output tile 128(c) x 128(vd). Two K-phases into one accumulator.
// ---------------------------------------------------------------------------
__global__ __launch_bounds__(256, 2) void reads_kernel(
    const bf16s* __restrict__ outb, const bf16s* __restrict__ Wst,
    const bf16s* __restrict__ Pm, const bf16s* __restrict__ vTs,
    bf16s* __restrict__ readsb, const float* __restrict__ p_decay) {
    const int ci = blockIdx.x & 7, vi = blockIdx.x >> 3;
    const int j = blockIdx.y, b = blockIdx.z;
    __shared__ bf16s sA[128 * 64];
    __shared__ bf16s sB[128 * 64];
    const int tid = threadIdx.x;
    const int wave = tid >> 6, lane = tid & 63;
    const int wm = wave >> 1, wn = wave & 1;
    const int ln15 = lane & 15, q = lane >> 4;
    const int sr = tid >> 3;
    const int sf = (tid & 7) ^ (sr & 7);
    const float lg = __log2f(1.0f / (1.0f + __expf(-p_decay[0])));
    f32x4 acc[4][4] = {};
    if (j > 0) {
        const bf16s* gA = outb + ((long)b * 4096 + j * 1024 + ci * 128 + sr) * 768 + sf * 8;
        const bf16s* gB = Wst + ((long)(b * 4 + j) * 768 + vi * 128 + sr) * 768 + sf * 8;
        for (int kt = 0; kt < 12; ++kt) {
            __syncthreads();
            stage128(sA, gA, 768, wave);
            stage128(sB, gB, 768, wave);
            gA += 64; gB += 64;
            asm volatile("s_waitcnt vmcnt(0)" ::: "memory");
            __syncthreads();
#pragma unroll
            for (int kk = 0; kk < 2; ++kk) {
                short8 af[4], bf_[4];
#pragma unroll
                for (int i = 0; i < 4; ++i) af[i] = fragr(sA, wm * 64 + i * 16 + ln15, kk, q);
#pragma unroll
                for (int jj = 0; jj < 4; ++jj) bf_[jj] = fragr(sB, wn * 64 + jj * 16 + ln15, kk, q);
#pragma unroll
                for (int i = 0; i < 4; ++i)
#pragma unroll
                    for (int jj = 0; jj < 4; ++jj) acc[i][jj] = MFMA(af[i], bf_[jj], acc[i][jj]);
            }
        }
#pragma unroll
        for (int i = 0; i < 4; ++i) {
            int cb_ = ci * 128 + wm * 64 + i * 16 + q * 4;
#pragma unroll
            for (int e = 0; e < 4; ++e) {
                float s = exp2f(lg * (float)(cb_ + e));
#pragma unroll
                for (int jj = 0; jj < 4; ++jj) acc[i][jj][e] *= s;
            }
        }
    }
    {
        const bf16s* gA = Pm + ((long)(b * 4 + j) << 20) + (long)(ci * 128 + sr) * 1024 + sf * 8;
        const bf16s* gB = vTs + ((long)b * 768 + vi * 128 + sr) * 4096 + j * 1024 + sf * 8;
        const int nkt = 2 * (ci + 1);
        for (int kt = 0; kt < nkt; ++kt) {
            __syncthreads();
            stage128(sA, gA, 1024, wave);
            stage128(sB, gB, 4096, wave);
            gA += 64; gB += 64;
            asm volatile("s_waitcnt vmcnt(0)" ::: "memory");
            __syncthreads();
#pragma unroll
            for (int kk = 0; kk < 2; ++kk) {
                short8 af[4], bf_[4];
#pragma unroll
                for (int i = 0; i < 4; ++i) af[i] = fragr(sA, wm * 64 + i * 16 + ln15, kk, q);
#pragma unroll
                for (int jj = 0; jj < 4; ++jj) bf_[jj] = fragr(sB, wn * 64 + jj * 16 + ln15, kk, q);
#pragma unroll
                for (int i = 0; i < 4; ++i)
#pragma unroll
                    for (int jj = 0; jj < 4; ++jj) acc[i][jj] = MFMA(af[i], bf_[jj], acc[i][jj]);
            }
        }
    }
#pragma unroll
    for (int i = 0; i < 4; ++i)
#pragma unroll
        for (int jj = 0; jj < 4; ++jj) {
            long tb = (long)j * 1024 + ci * 128 + wm * 64 + i * 16 + q * 4;
            long nc = vi * 128 + wn * 64 + jj * 16 + ln15;
#pragma unroll
            for (int e = 0; e < 4; ++e)
                readsb[((long)b * 4096 + tb + e) * 768 + nc] = f2bf(acc[i][jj][e]);
        }
}

// ---------------------------------------------------------------------------
extern "C" void kernel_launch(void* const* d_in, const int* in_sizes, int n_in,
                              void* d_out, int out_size, void* d_ws, size_t ws_size,
                              hipStream_t stream) {
    (void)in_sizes; (void)n_in; (void)out_size;
    const float* x      = (const float*)d_in[0];
    const float* norm_w = (const float*)d_in[1];
    const float* proj_w = (const float*)d_in[2];
    const float* gate_w = (const float*)d_in[3];
    const float* conv_w = (const float*)d_in[4];
    const float* conv_b = (const float*)d_in[5];
    const float* op_w   = (const float*)d_in[6];
    const float* wr_w   = (const float*)d_in[7];
    const float* rd_w   = (const float*)d_in[8];
    const float* decay  = (const float*)d_in[9];
    const float* la     = (const float*)d_in[10];

    // -------- workspace layout (liveness overlays), ~312.4 MB total --------
    char* ws = (char*)d_ws;
    size_t off = 0;
    auto alloc = [&](size_t bytes) { void* p = ws + off; off += (bytes + 255) & ~(size_t)255; return p; };
    bf16s* w_pg = (bf16s*)alloc(3072l * 768 * 2);          // 4.7 MB
    bf16s* w_op = (bf16s*)alloc(768l * 1536 * 2);          // 2.4 MB
    bf16s* w_wr = (bf16s*)alloc(768l * 768 * 2);           // 1.2 MB
    bf16s* w_rd = (bf16s*)alloc(768l * 768 * 2);           // 1.2 MB
    bf16s* RA   = (bf16s*)alloc(32768l * 768 * 2);         // 50.3 MB: xn | vTs
    bf16s* RB   = (bf16s*)alloc(2 * 32768l * 768 * 2);     // 100.7 MB: pg | vb+oTs | P'
    bf16s* RC   = (bf16s*)alloc(2 * 32768l * 768 * 2);     // 100.7 MB: vg | Wst+reads
    bf16s* RE   = (bf16s*)alloc(32768l * 768 * 2);         // 50.3 MB: outb
    if (ws_size < off) return;   // diagnostic guard: fail clean, don't fault

    bf16s* xn    = RA;
    bf16s* vTs   = RA;
    bf16s* pgH   = RB;                     // 16384 x 3072 (one M-half)
    bf16s* vb    = RB;                     // [0:50.3 MB]
    bf16s* oTs   = RB + 25165824;          // [50.3:100.7 MB]
    bf16s* Pm    = RB;                     // 67.1 MB (after vb & oTs are dead)
    bf16s* vg    = RC;                     // 32768 x 1536
    bf16s* Wst   = RC;                     // 37.75 MB (after vg dead)
    bf16s* readsb= RC + 18874368;          // [37.75:88.1 MB]
    bf16s* outb  = RE;

    hipLaunchKernelGGL(cast_w_kernel, dim3(18432), dim3(256), 0, stream,
                       proj_w, gate_w, op_w, wr_w, rd_w, w_pg, w_op, w_wr, w_rd);
    hipLaunchKernelGGL(rmsnorm_kernel, dim3(32768), dim3(256), 0, stream, x, norm_w, xn);
    // proj+gate GEMM + conv, split at the batch-4 boundary (no conv halo)
    for (int h = 0; h < 2; ++h) {
        hipLaunchKernelGGL(HIP_KERNEL_NAME(gemm_kernel<0>), dim3(24, 128), dim3(256), 0, stream,
                           xn + (long)h * 16384 * 768, w_pg, 768, 3072, pgH,
                           (const float*)nullptr, (const bf16s*)nullptr, la, (float*)nullptr);
        hipLaunchKernelGGL(conv_kernel, dim3(1024), dim3(192), 0, stream,
                           pgH, conv_w, conv_b, vg + (long)h * 16384 * 1536);
    }
    hipLaunchKernelGGL(HIP_KERNEL_NAME(gemm_kernel<0>), dim3(6, 256), dim3(256), 0, stream,
                       vg, w_op, 1536, 768, outb,
                       (const float*)nullptr, (const bf16s*)nullptr, la, (float*)nullptr);
    hipLaunchKernelGGL(HIP_KERNEL_NAME(gemm_kernel<0>), dim3(6, 256), dim3(256), 0, stream,
                       outb, w_wr, 768, 768, vb,
                       (const float*)nullptr, (const bf16s*)nullptr, la, (float*)nullptr);
    hipLaunchKernelGGL(HIP_KERNEL_NAME(transpose_kernel<1, 0>), dim3(12, 64, 8), dim3(256), 0, stream,
                       outb, oTs, decay);
    hipLaunchKernelGGL(HIP_KERNEL_NAME(transpose_kernel<0, 1>), dim3(12, 64, 8), dim3(256), 0, stream,
                       vb, vTs, decay);
    hipLaunchKernelGGL(wstate_kernel, dim3(36, 8), dim3(256), 0, stream,
                       vTs, oTs, Wst, decay);
    hipLaunchKernelGGL(pmat_kernel, dim3(64, 4, 8), dim3(256), 0, stream,
                       outb, Pm, decay);          // clobbers vb+oTs (both dead)
    hipLaunchKernelGGL(reads_kernel, dim3(48, 4, 8), dim3(256), 0, stream,
                       outb, Wst, Pm, vTs, readsb, decay);
    hipLaunchKernelGGL(HIP_KERNEL_NAME(gemm_kernel<1>), dim3(6, 256), dim3(256), 0, stream,
                       readsb, w_rd, 768, 768, (bf16s*)nullptr,
                       x, outb, la, (float*)d_out);
}